// Round 15
// baseline (153.218 us; speedup 1.0000x reference)
//
#include <hip/hip_runtime.h>

// Problem constants
#define U_CNT 784   // H*W = 28*28 (both u and v extents)
#define DKH   128   // key/value head dim
#define DD    512   // input channel dim
#define NS    16    // support classes

typedef short bf16x8 __attribute__((ext_vector_type(8)));
typedef float f32x4  __attribute__((ext_vector_type(4)));

__device__ __forceinline__ unsigned short f2bf(float f) {
  unsigned u = __builtin_bit_cast(unsigned, f);
  u += 0x7fffu + ((u >> 16) & 1u);   // round-to-nearest-even
  return (unsigned short)(u >> 16);
}

// Sum across the 4 row-groups (lanes l, l^16, l^32, l^48) using gfx950's
// VALU permlane swaps (~4cy) instead of ds_swizzle (~120cy LDS latency).
// Copies are materialized INSIDE the asm via v_mov into two earlyclobber
// outputs (guaranteed distinct registers; tied-operand version let copy-prop
// alias both operands to one register -> garbage).
__device__ __forceinline__ float rowg_sum(float x) {
  float a, b;
  asm("v_mov_b32 %0, %2\n\t"
      "v_mov_b32 %1, %2\n\t"
      "v_permlane16_swap_b32 %0, %1"
      : "=&v"(a), "=&v"(b) : "v"(x));
  float s = a + b;                    // s[l] = x[l] + x[l^16]
  float c, d;
  asm("v_mov_b32 %0, %2\n\t"
      "v_mov_b32 %1, %2\n\t"
      "v_permlane32_swap_b32 %0, %1"
      : "=&v"(c), "=&v"(d) : "v"(s));
  return c + d;                       // full sum over {l, l^16, l^32, l^48}
}

// Fragment-major layouts (bf16), so MFMA fragment loads are 64x16B contiguous:
//   sk_f[v][c(16)][class(16)][8]   : frag(v,s) @ v*2048 + (s*4+rowg)*128 + col*8
//   q_f [b][ut(49)][c(16)][ul(16)][8]: frag(ut,s) @ b*100352 + ut*2048 + (s*4+rowg)*128 + col*8
// q_f is scaled by (1/sqrt(128)) * log2(e) so score can use bare v_exp_f32.
// Wkv fragment-major (R4): each Af load is one contiguous 1KB transaction.
// R14: align fused into score (score owns all u per (b, v-slice)).
// R15: score's k-accumulation split into 4 INDEPENDENT MFMAs + VALU add tree
// (dependent-MFMA chain latency was the last untested invariant).

// ---------------------------------------------------------------- K0: cast W
__global__ __launch_bounds__(256)
void cast_w(const float* __restrict__ Wk, const float* __restrict__ Wv,
            unsigned short* __restrict__ Wkv_f) {
  int g = blockIdx.x * 256 + threadIdx.x;   // 16384 = 256 fidx * 64 lanes
  int fidx = g >> 6, l = g & 63;
  int f = fidx >> 4, rd = (fidx >> 2) & 3, ds = fidx & 3;
  int row = f * 16 + (l & 15);
  int dbase = rd * 128 + ds * 32 + (l >> 4) * 8;
  const float* src = (row < 128) ? (Wk + row * DD + dbase) : (Wv + (row - 128) * DD + dbase);
  unsigned short* dst = Wkv_f + (size_t)fidx * 512 + l * 8;
#pragma unroll
  for (int j = 0; j < 8; ++j) dst[j] = f2bf(src[j]);
}

// ------------------------------------------------------------- K1: projection
// R11 form (best known): PB=16, grid 49x24, p-major line-coalesced staging,
// fragment-major Wkv (1KB contiguous Af loads).
__global__ __launch_bounds__(256, 4)
void proj_kernel(const float* __restrict__ query, const float* __restrict__ support,
                 const unsigned short* __restrict__ Wkv_f,
                 unsigned short* __restrict__ q_f, unsigned short* __restrict__ sk_f,
                 float* __restrict__ sv_t, float* __restrict__ S1p, float* __restrict__ S2p) {
  constexpr int PB = 16;           // p per block
  constexpr int DR = 128;          // d per round
  constexpr int RW = DR + 8;       // padded LDS row (ushorts) per p: 272B, 16B-aligned
  __shared__ __align__(16) unsigned short xs[2][PB * RW];   // 2 x 4352B
  int pc = blockIdx.x;             // 0..48
  int m  = blockIdx.y;             // 0..23
  int tid = threadIdx.x;
  int p0 = pc * PB;
  const float* X = (m < 8) ? (query + (size_t)m * DD * U_CNT)
                           : (support + (size_t)(m - 8) * DD * U_CNT);
  int r4 = tid >> 2, sub = tid & 3;               // p-major: 4 lanes share one row line
  const float* xrow = X + p0 + sub * 4;

  float4 vbuf[2];
  auto loadR = [&](int rd) {
    const float* s = xrow + (size_t)(rd * DR + r4) * U_CNT;
    vbuf[0] = *(const float4*)(s);
    vbuf[1] = *(const float4*)(s + (size_t)64 * U_CNT);
  };
  auto storeR = [&](int bb) {
    unsigned short* d0 = &xs[bb][(sub * 4) * RW + r4];
#pragma unroll
    for (int i = 0; i < 2; ++i) {
      unsigned short* dp = d0 + i * 64;
      dp[0]      = f2bf(vbuf[i].x); dp[RW]     = f2bf(vbuf[i].y);
      dp[2 * RW] = f2bf(vbuf[i].z); dp[3 * RW] = f2bf(vbuf[i].w);
    }
  };

  int wave = tid >> 6, l = tid & 63;
  int col = l & 15, rowg = l >> 4;

  f32x4 acc[4];
  f32x4 zero = {0.f, 0.f, 0.f, 0.f};
#pragma unroll
  for (int rr = 0; rr < 4; ++rr) acc[rr] = zero;

  loadR(0); storeR(0);
  __syncthreads();
  for (int rd = 0; rd < 4; ++rd) {
    if (rd < 3) loadR(rd + 1);        // in flight during compute
    int bb = rd & 1;
#pragma unroll
    for (int ds = 0; ds < 4; ++ds) {
      int dl = ds * 32 + rowg * 8;
      bf16x8 Af[4];
#pragma unroll
      for (int rr = 0; rr < 4; ++rr)
        Af[rr] = *(const bf16x8*)(Wkv_f +
                 (size_t)((((wave * 4 + rr) * 4 + rd) * 4 + ds) * 512) + l * 8);
      bf16x8 bf = *(const bf16x8*)(&xs[bb][col * RW + dl]);
#pragma unroll
      for (int rr = 0; rr < 4; ++rr)
        acc[rr] = __builtin_amdgcn_mfma_f32_16x16x32_bf16(Af[rr], bf, acc[rr], 0, 0, 0);
    }
    if (rd < 3) {
      __syncthreads();                 // all waves done reading xs[bb^1]'s old data
      storeR((rd + 1) & 1);
      __syncthreads();                 // next round's tile visible
    }
  }

  // ------------------------------- epilogue ---------------------------------
  if (m < 8) {
    if (wave < 2) {
      // rows 0..127 -> q_f fragment-major (scaled bf16); ut = pc
#pragma unroll
      for (int rr = 0; rr < 4; ++rr) {
        int r = wave * 4 + rr;          // 0..7
        const float sc = 0.08838834764831845f * 1.4426950408889634f;  // 1/sqrt(128) * log2(e)
        ushort4 o;
        o.x = f2bf(acc[rr][0] * sc); o.y = f2bf(acc[rr][1] * sc);
        o.z = f2bf(acc[rr][2] * sc); o.w = f2bf(acc[rr][3] * sc);
        size_t off = (size_t)m * 100352 + (size_t)pc * 2048 +
                     (size_t)(2 * r + (rowg >> 1)) * 128 + col * 8 + (rowg & 1) * 4;
        *(ushort4*)(q_f + off) = o;
      }
    } else {
      float s1 = 0.f;
#pragma unroll
      for (int rr = 0; rr < 4; ++rr) {
        int r = wave * 4 + rr;          // 8..15
#pragma unroll
        for (int j = 0; j < 4; ++j) {
          float x = acc[rr][j];
          s1 += x * x;
          float xsum = x;
          xsum += __shfl_xor(xsum, 1, 64); xsum += __shfl_xor(xsum, 2, 64);
          xsum += __shfl_xor(xsum, 4, 64); xsum += __shfl_xor(xsum, 8, 64);
          if (col == 0)
            S2p[((size_t)pc * 8 + m) * DKH + (r - 8) * 16 + rowg * 4 + j] = xsum;
        }
      }
#pragma unroll
      for (int o = 32; o >= 1; o >>= 1) s1 += __shfl_xor(s1, o, 64);
      if (l == 0) S1p[((size_t)(wave - 2) * 49 + pc) * 8 + m] = s1;
    }
  } else {
    int img = m - 8;
    if (wave < 2) {
#pragma unroll
      for (int rr = 0; rr < 4; ++rr) {
        int r = wave * 4 + rr;          // 0..7
        ushort4 o;
        o.x = f2bf(acc[rr][0]); o.y = f2bf(acc[rr][1]);
        o.z = f2bf(acc[rr][2]); o.w = f2bf(acc[rr][3]);
        size_t off = (size_t)(p0 + col) * 2048 +
                     (size_t)(2 * r + (rowg >> 1)) * 128 + img * 8 + (rowg & 1) * 4;
        *(ushort4*)(sk_f + off) = o;
      }
    } else {
#pragma unroll
      for (int rr = 0; rr < 4; ++rr) {
        int r = wave * 4 + rr;
        int kb = (r - 8) * 16 + rowg * 4;
        float4 o = make_float4(acc[rr][0], acc[rr][1], acc[rr][2], acc[rr][3]);
        *(float4*)(sv_t + (size_t)(img * U_CNT + p0 + col) * DKH + kb) = o;
      }
    }
  }
}

// ------------------------- K3: scores + softmax_n + sum_u + ALIGN (fused)
// R14 structure: 784 blocks = 8 b x 98 vb; each block owns 8 v x all 49
// u-tiles; align fused into epilogue. XCD pin kept.
// R15: the 4 k-slice MFMAs per v are now INDEPENDENT (C-in = zero) and
// combined by a 2-level VALU add tree. Across 6 prior variants score was
// pinned at 42-46us with nothing saturated (MfmaUtil 17, VALU 35, HBM 11,
// occ 20) -- the only untested invariant was the 4-deep dependent-MFMA
// chain (~250cy serial latency/iter, unhideable at 3 waves/SIMD). This
// trades it for ~5cy-issue parallel MFMAs + ~16cy of adds.
__global__ __launch_bounds__(256, 3)
void score_kernel(const unsigned short* __restrict__ q_f,
                  const unsigned short* __restrict__ sk_f,
                  const float* __restrict__ sv_t,
                  float* __restrict__ T1p, float* __restrict__ T2p) {
  int bx = blockIdx.x;            // 784 = 8 b * 98 vb
  int b  = bx & 7;
  int vb = bx >> 3;               // 0..97
  int wv = threadIdx.x >> 6;
  int l  = threadIdx.x & 63;
  int col = l & 15, rowg = l >> 4;
  int vbase = vb * 8 + wv * 2;    // global v of this wave's v-local 0

  bf16x8 A[2][4];
#pragma unroll
  for (int v = 0; v < 2; ++v) {
    const unsigned short* ap = sk_f + (size_t)(vbase + v) * 2048 + rowg * 128 + col * 8;
#pragma unroll
    for (int s = 0; s < 4; ++s) A[v][s] = *(const bf16x8*)(ap + s * 512);
  }

  float wl[2][4];
#pragma unroll
  for (int v = 0; v < 2; ++v)
#pragma unroll
    for (int j = 0; j < 4; ++j) wl[v][j] = 0.f;

  const unsigned short* qb = q_f + (size_t)b * 100352 + rowg * 128 + col * 8;
  f32x4 zero = {0.f, 0.f, 0.f, 0.f};

  bf16x8 B0 = *(const bf16x8*)(qb);
  bf16x8 B1 = *(const bf16x8*)(qb + 512);
  bf16x8 B2 = *(const bf16x8*)(qb + 1024);
  bf16x8 B3 = *(const bf16x8*)(qb + 1536);

  for (int it = 0; it < 49; ++it) {
    int nit = (it + 1 < 49) ? it + 1 : it;
    const unsigned short* qp = qb + (size_t)nit * 2048;
    bf16x8 N0 = *(const bf16x8*)(qp);
    bf16x8 N1 = *(const bf16x8*)(qp + 512);
    bf16x8 N2 = *(const bf16x8*)(qp + 1024);
    bf16x8 N3 = *(const bf16x8*)(qp + 1536);

    // 8 fully independent MFMAs (4 k-slices x 2 v), then VALU add trees.
    f32x4 p0[2], p1[2], p2[2], p3[2];
#pragma unroll
    for (int v = 0; v < 2; ++v)
      p0[v] = __builtin_amdgcn_mfma_f32_16x16x32_bf16(A[v][0], B0, zero, 0, 0, 0);
#pragma unroll
    for (int v = 0; v < 2; ++v)
      p1[v] = __builtin_amdgcn_mfma_f32_16x16x32_bf16(A[v][1], B1, zero, 0, 0, 0);
#pragma unroll
    for (int v = 0; v < 2; ++v)
      p2[v] = __builtin_amdgcn_mfma_f32_16x16x32_bf16(A[v][2], B2, zero, 0, 0, 0);
#pragma unroll
    for (int v = 0; v < 2; ++v)
      p3[v] = __builtin_amdgcn_mfma_f32_16x16x32_bf16(A[v][3], B3, zero, 0, 0, 0);

    float e[2][4], ps[2];
#pragma unroll
    for (int v = 0; v < 2; ++v) {
      f32x4 acc = (p0[v] + p1[v]) + (p2[v] + p3[v]);
      e[v][0] = __builtin_amdgcn_exp2f(acc[0]);
      e[v][1] = __builtin_amdgcn_exp2f(acc[1]);
      e[v][2] = __builtin_amdgcn_exp2f(acc[2]);
      e[v][3] = __builtin_amdgcn_exp2f(acc[3]);
      ps[v] = (e[v][0] + e[v][1]) + (e[v][2] + e[v][3]);
    }
#pragma unroll
    for (int v = 0; v < 2; ++v) ps[v] = rowg_sum(ps[v]);
#pragma unroll
    for (int v = 0; v < 2; ++v) {
      float r = __builtin_amdgcn_rcpf(ps[v]);
      wl[v][0] += e[v][0] * r; wl[v][1] += e[v][1] * r;
      wl[v][2] += e[v][2] * r; wl[v][3] += e[v][3] * r;
    }
    B0 = N0; B1 = N1; B2 = N2; B3 = N3;
  }

  // u-sum across the 16 lane-columns
#pragma unroll
  for (int v = 0; v < 2; ++v)
#pragma unroll
    for (int j = 0; j < 4; ++j) {
      float x = wl[v][j];
      x += __shfl_xor(x, 1, 64); x += __shfl_xor(x, 2, 64);
      x += __shfl_xor(x, 4, 64); x += __shfl_xor(x, 8, 64);
      wl[v][j] = x;
    }
  __shared__ float wst[4][2][16];   // [wave][v_local][class]
#pragma unroll
  for (int v = 0; v < 2; ++v)
    if (col == v) {
#pragma unroll
      for (int j = 0; j < 4; ++j) wst[wv][v][rowg * 4 + j] = wl[v][j];
    }
  __syncthreads();

  // ---- fused align: a[v][k] = sum_n w[v][n]*sv_t[n][v][k]; T1 += a^2;
  //      T2 partial = sum_v a. Lanes own 2 consecutive k (k0 = l*2).
  __shared__ float red[4][128];
  __shared__ float t1s[4];
  int k0 = l * 2;
  float a00 = 0.f, a01 = 0.f, a10 = 0.f, a11 = 0.f;   // [v][kk]
#pragma unroll
  for (int n = 0; n < NS; ++n) {
    float w0 = wst[wv][0][n], w1 = wst[wv][1][n];
    const float* p0 = sv_t + ((size_t)n * U_CNT + vbase) * DKH + k0;
    float2 s0 = *(const float2*)(p0);
    float2 s1 = *(const float2*)(p0 + DKH);
    a00 += w0 * s0.x; a01 += w0 * s0.y;
    a10 += w1 * s1.x; a11 += w1 * s1.y;
  }
  float t1 = a00 * a00 + a01 * a01 + a10 * a10 + a11 * a11;
  red[wv][k0] = a00 + a10;
  red[wv][k0 + 1] = a01 + a11;
#pragma unroll
  for (int o = 32; o >= 1; o >>= 1) t1 += __shfl_xor(t1, o, 64);
  if (l == 0) t1s[wv] = t1;
  __syncthreads();
  int t = threadIdx.x;
  if (t < 128)
    T2p[((size_t)vb * 8 + b) * DKH + t] = red[0][t] + red[1][t] + red[2][t] + red[3][t];
  if (t == 128)
    T1p[vb * 8 + b] = t1s[0] + t1s[1] + t1s[2] + t1s[3];
}

// ------------------------------- K5a: parallel partial reduction (40 blocks)
__global__ __launch_bounds__(256)
void reduce_partials(const float* __restrict__ S1p, const float* __restrict__ T1p,
                     const float* __restrict__ S2p, const float* __restrict__ T2p,
                     float* __restrict__ S2, float* __restrict__ T2,
                     float* __restrict__ ST1) {
  __shared__ float smem[264];
  int bx = blockIdx.x, t = threadIdx.x;
  if (bx < 32) {
    int b = bx >> 2, kq = bx & 3;
    int kl = t & 31, g = t >> 5;           // 8 groups x 32 k-lanes
    int k = kq * 32 + kl;
    float s = 0.f;
    for (int w = g; w < 98; w += 8)
      s += T2p[((size_t)w * 8 + b) * DKH + k];
    smem[g * 32 + kl] = s;
    __syncthreads();
    if (t < 32) {
      float v = 0.f;
#pragma unroll
      for (int g2 = 0; g2 < 8; ++g2) v += smem[g2 * 32 + t];
      T2[b * DKH + kq * 32 + t] = v;
    }
  } else {
    int b = bx - 32;
    int k = t & 127, h = t >> 7;
    float s = 0.f;
    for (int w = h; w < 49; w += 2)
      s += S2p[((size_t)w * 8 + b) * DKH + k];
    if (h == 1) smem[k] = s;
    __syncthreads();
    if (h == 0) S2[b * DKH + k] = s + smem[k];
    float c = 0.f;
    for (int i = t; i < 98; i += 256) c += S1p[i * 8 + b];
    for (int i = t; i < 98; i += 256) c += T1p[i * 8 + b];
#pragma unroll
    for (int o = 32; o >= 1; o >>= 1) c += __shfl_xor(c, o, 64);
    if ((t & 63) == 0) smem[256 + (t >> 6)] = c;
    __syncthreads();
    if (t == 0) ST1[b] = smem[256] + smem[257] + smem[258] + smem[259];
  }
}

// ----------------------------------------------------------------- K5b: final
__global__ void final_kernel(const float* __restrict__ S2, const float* __restrict__ T2,
                             const float* __restrict__ ST1, float* __restrict__ out) {
  int b = blockIdx.x, t = threadIdx.x;  // 128 threads
  float p = S2[b * DKH + t] * T2[b * DKH + t];
#pragma unroll
  for (int o = 32; o >= 1; o >>= 1) p += __shfl_xor(p, o, 64);
  __shared__ float s2[2];
  if ((t & 63) == 0) s2[t >> 6] = p;
  __syncthreads();
  if (t == 0)
    out[b] = (784.0f * ST1[b] - 2.0f * (s2[0] + s2[1])) * (1.0f / (784.0f * 784.0f));
}

// ----------------------------------------------------------------- launcher
extern "C" void kernel_launch(void* const* d_in, const int* in_sizes, int n_in,
                              void* d_out, int out_size, void* d_ws, size_t ws_size,
                              hipStream_t stream) {
  const float* query   = (const float*)d_in[0];
  const float* support = (const float*)d_in[1];
  const float* Wk      = (const float*)d_in[2];
  const float* Wv      = (const float*)d_in[3];
  float* out = (float*)d_out;
  char* ws = (char*)d_ws;

  // workspace layout (256B-aligned)
  unsigned short* Wkv  = (unsigned short*)(ws + 0);          //  256KB (fragment-major)
  unsigned short* q_f  = (unsigned short*)(ws + 262144);     //  bf16 [8][49][16][16][8] 1.53MB
  unsigned short* sk_f = (unsigned short*)(ws + 1867776);    //  bf16 [784][16][16][8]   3.06MB
  float*          sv_t = (float*)(ws + 5079040);             //  f32  [16][784][128]     6.13MB
  float*          T1p  = (float*)(ws + 11501568);            //  [98][8]
  float*          S1p  = (float*)(ws + 11504896);            //  [98][8]
  float*          S2p  = (float*)(ws + 11508224);            //  [49][8][128]
  float*          T2p  = (float*)(ws + 11708928);            //  [98][8][128]
  float*          S2   = (float*)(ws + 12110336);            //  [8][128]
  float*          T2   = (float*)(ws + 12114432);            //  [8][128]
  float*          ST1  = (float*)(ws + 12118528);            //  [8]
  if (ws_size < (size_t)12118784) return;

  cast_w<<<64, 256, 0, stream>>>(Wk, Wv, Wkv);
  proj_kernel<<<dim3(49, 24), 256, 0, stream>>>(query, support, Wkv, q_f, sk_f, sv_t, S1p, S2p);
  score_kernel<<<784, 256, 0, stream>>>(q_f, sk_f, sv_t, T1p, T2p);
  reduce_partials<<<40, 256, 0, stream>>>(S1p, T1p, S2p, T2p, S2, T2, ST1);
  final_kernel<<<8, 128, 0, stream>>>(S2, T2, ST1, out);
}

// Round 16
// 144.236 us; speedup vs baseline: 1.0623x; 1.0623x over previous
//
#include <hip/hip_runtime.h>

// Problem constants
#define U_CNT 784   // H*W = 28*28 (both u and v extents)
#define DKH   128   // key/value head dim
#define DD    512   // input channel dim
#define NS    16    // support classes

typedef short bf16x8 __attribute__((ext_vector_type(8)));
typedef float f32x4  __attribute__((ext_vector_type(4)));

__device__ __forceinline__ unsigned short f2bf(float f) {
  unsigned u = __builtin_bit_cast(unsigned, f);
  u += 0x7fffu + ((u >> 16) & 1u);   // round-to-nearest-even
  return (unsigned short)(u >> 16);
}

// Sum across the 4 row-groups (lanes l, l^16, l^32, l^48) using gfx950's
// VALU permlane swaps (~4cy) instead of ds_swizzle (~120cy LDS latency).
// Copies are materialized INSIDE the asm via v_mov into two earlyclobber
// outputs (guaranteed distinct registers; tied-operand version let copy-prop
// alias both operands to one register -> garbage).
__device__ __forceinline__ float rowg_sum(float x) {
  float a, b;
  asm("v_mov_b32 %0, %2\n\t"
      "v_mov_b32 %1, %2\n\t"
      "v_permlane16_swap_b32 %0, %1"
      : "=&v"(a), "=&v"(b) : "v"(x));
  float s = a + b;                    // s[l] = x[l] + x[l^16]
  float c, d;
  asm("v_mov_b32 %0, %2\n\t"
      "v_mov_b32 %1, %2\n\t"
      "v_permlane32_swap_b32 %0, %1"
      : "=&v"(c), "=&v"(d) : "v"(s));
  return c + d;                       // full sum over {l, l^16, l^32, l^48}
}

// Fragment-major layouts (bf16), so MFMA fragment loads are 64x16B contiguous:
//   sk_f[v][c(16)][class(16)][8]   : frag(v,s) @ v*2048 + (s*4+rowg)*128 + col*8
//   q_f [b][ut(49)][c(16)][ul(16)][8]: frag(ut,s) @ b*100352 + ut*2048 + (s*4+rowg)*128 + col*8
// q_f is scaled by (1/sqrt(128)) * log2(e) so score can use bare v_exp_f32.
// Wkv fragment-major (R4): each Af load is one contiguous 1KB transaction.
// R14: align fused into score (score owns all u per (b, v-slice)).
// R16: score XCD swizzle FLIPPED. The old pin (b = bx&7) co-located the 98
// blocks sharing q_f[b] (192KB) but spread each vb's sk+sv slice (96KB,
// 9.2MB total) across all 8 XCDs => sk/sv re-fetched per XCD (FETCH 38.5MB
// vs 10.7MB unique, 3.6x). New decode co-locates all 8 b of ~13 consecutive
// vb per XCD: per-XCD L2 set = q_f 1.53MB + 13x96KB = 2.8MB < 4MB, every
// sk/sv byte fetched by ONE XCD.

// ---------------------------------------------------------------- K0: cast W
__global__ __launch_bounds__(256)
void cast_w(const float* __restrict__ Wk, const float* __restrict__ Wv,
            unsigned short* __restrict__ Wkv_f) {
  int g = blockIdx.x * 256 + threadIdx.x;   // 16384 = 256 fidx * 64 lanes
  int fidx = g >> 6, l = g & 63;
  int f = fidx >> 4, rd = (fidx >> 2) & 3, ds = fidx & 3;
  int row = f * 16 + (l & 15);
  int dbase = rd * 128 + ds * 32 + (l >> 4) * 8;
  const float* src = (row < 128) ? (Wk + row * DD + dbase) : (Wv + (row - 128) * DD + dbase);
  unsigned short* dst = Wkv_f + (size_t)fidx * 512 + l * 8;
#pragma unroll
  for (int j = 0; j < 8; ++j) dst[j] = f2bf(src[j]);
}

// ------------------------------------------------------------- K1: projection
// R11 form (best known): PB=16, grid 49x24, p-major line-coalesced staging,
// fragment-major Wkv (1KB contiguous Af loads).
__global__ __launch_bounds__(256, 4)
void proj_kernel(const float* __restrict__ query, const float* __restrict__ support,
                 const unsigned short* __restrict__ Wkv_f,
                 unsigned short* __restrict__ q_f, unsigned short* __restrict__ sk_f,
                 float* __restrict__ sv_t, float* __restrict__ S1p, float* __restrict__ S2p) {
  constexpr int PB = 16;           // p per block
  constexpr int DR = 128;          // d per round
  constexpr int RW = DR + 8;       // padded LDS row (ushorts) per p: 272B, 16B-aligned
  __shared__ __align__(16) unsigned short xs[2][PB * RW];   // 2 x 4352B
  int pc = blockIdx.x;             // 0..48
  int m  = blockIdx.y;             // 0..23
  int tid = threadIdx.x;
  int p0 = pc * PB;
  const float* X = (m < 8) ? (query + (size_t)m * DD * U_CNT)
                           : (support + (size_t)(m - 8) * DD * U_CNT);
  int r4 = tid >> 2, sub = tid & 3;               // p-major: 4 lanes share one row line
  const float* xrow = X + p0 + sub * 4;

  float4 vbuf[2];
  auto loadR = [&](int rd) {
    const float* s = xrow + (size_t)(rd * DR + r4) * U_CNT;
    vbuf[0] = *(const float4*)(s);
    vbuf[1] = *(const float4*)(s + (size_t)64 * U_CNT);
  };
  auto storeR = [&](int bb) {
    unsigned short* d0 = &xs[bb][(sub * 4) * RW + r4];
#pragma unroll
    for (int i = 0; i < 2; ++i) {
      unsigned short* dp = d0 + i * 64;
      dp[0]      = f2bf(vbuf[i].x); dp[RW]     = f2bf(vbuf[i].y);
      dp[2 * RW] = f2bf(vbuf[i].z); dp[3 * RW] = f2bf(vbuf[i].w);
    }
  };

  int wave = tid >> 6, l = tid & 63;
  int col = l & 15, rowg = l >> 4;

  f32x4 acc[4];
  f32x4 zero = {0.f, 0.f, 0.f, 0.f};
#pragma unroll
  for (int rr = 0; rr < 4; ++rr) acc[rr] = zero;

  loadR(0); storeR(0);
  __syncthreads();
  for (int rd = 0; rd < 4; ++rd) {
    if (rd < 3) loadR(rd + 1);        // in flight during compute
    int bb = rd & 1;
#pragma unroll
    for (int ds = 0; ds < 4; ++ds) {
      int dl = ds * 32 + rowg * 8;
      bf16x8 Af[4];
#pragma unroll
      for (int rr = 0; rr < 4; ++rr)
        Af[rr] = *(const bf16x8*)(Wkv_f +
                 (size_t)((((wave * 4 + rr) * 4 + rd) * 4 + ds) * 512) + l * 8);
      bf16x8 bf = *(const bf16x8*)(&xs[bb][col * RW + dl]);
#pragma unroll
      for (int rr = 0; rr < 4; ++rr)
        acc[rr] = __builtin_amdgcn_mfma_f32_16x16x32_bf16(Af[rr], bf, acc[rr], 0, 0, 0);
    }
    if (rd < 3) {
      __syncthreads();                 // all waves done reading xs[bb^1]'s old data
      storeR((rd + 1) & 1);
      __syncthreads();                 // next round's tile visible
    }
  }

  // ------------------------------- epilogue ---------------------------------
  if (m < 8) {
    if (wave < 2) {
      // rows 0..127 -> q_f fragment-major (scaled bf16); ut = pc
#pragma unroll
      for (int rr = 0; rr < 4; ++rr) {
        int r = wave * 4 + rr;          // 0..7
        const float sc = 0.08838834764831845f * 1.4426950408889634f;  // 1/sqrt(128) * log2(e)
        ushort4 o;
        o.x = f2bf(acc[rr][0] * sc); o.y = f2bf(acc[rr][1] * sc);
        o.z = f2bf(acc[rr][2] * sc); o.w = f2bf(acc[rr][3] * sc);
        size_t off = (size_t)m * 100352 + (size_t)pc * 2048 +
                     (size_t)(2 * r + (rowg >> 1)) * 128 + col * 8 + (rowg & 1) * 4;
        *(ushort4*)(q_f + off) = o;
      }
    } else {
      float s1 = 0.f;
#pragma unroll
      for (int rr = 0; rr < 4; ++rr) {
        int r = wave * 4 + rr;          // 8..15
#pragma unroll
        for (int j = 0; j < 4; ++j) {
          float x = acc[rr][j];
          s1 += x * x;
          float xsum = x;
          xsum += __shfl_xor(xsum, 1, 64); xsum += __shfl_xor(xsum, 2, 64);
          xsum += __shfl_xor(xsum, 4, 64); xsum += __shfl_xor(xsum, 8, 64);
          if (col == 0)
            S2p[((size_t)pc * 8 + m) * DKH + (r - 8) * 16 + rowg * 4 + j] = xsum;
        }
      }
#pragma unroll
      for (int o = 32; o >= 1; o >>= 1) s1 += __shfl_xor(s1, o, 64);
      if (l == 0) S1p[((size_t)(wave - 2) * 49 + pc) * 8 + m] = s1;
    }
  } else {
    int img = m - 8;
    if (wave < 2) {
#pragma unroll
      for (int rr = 0; rr < 4; ++rr) {
        int r = wave * 4 + rr;          // 0..7
        ushort4 o;
        o.x = f2bf(acc[rr][0]); o.y = f2bf(acc[rr][1]);
        o.z = f2bf(acc[rr][2]); o.w = f2bf(acc[rr][3]);
        size_t off = (size_t)(p0 + col) * 2048 +
                     (size_t)(2 * r + (rowg >> 1)) * 128 + img * 8 + (rowg & 1) * 4;
        *(ushort4*)(sk_f + off) = o;
      }
    } else {
#pragma unroll
      for (int rr = 0; rr < 4; ++rr) {
        int r = wave * 4 + rr;
        int kb = (r - 8) * 16 + rowg * 4;
        float4 o = make_float4(acc[rr][0], acc[rr][1], acc[rr][2], acc[rr][3]);
        *(float4*)(sv_t + (size_t)(img * U_CNT + p0 + col) * DKH + kb) = o;
      }
    }
  }
}

// ------------------------- K3: scores + softmax_n + sum_u + ALIGN (fused)
// R14 loop structure (best: 46us). R16: block decode swizzled so each XCD
// owns all 8 b of ~13 consecutive vb (see header comment): x = bx&7 selects
// the XCD under round-robin dispatch; g = x*98 + (bx>>3) linearizes (b,vb)
// pairs so consecutive g share vb.
__global__ __launch_bounds__(256, 3)
void score_kernel(const unsigned short* __restrict__ q_f,
                  const unsigned short* __restrict__ sk_f,
                  const float* __restrict__ sv_t,
                  float* __restrict__ T1p, float* __restrict__ T2p) {
  int bx = blockIdx.x;            // 784
  int x  = bx & 7;                // XCD (round-robin dispatch)
  int g  = x * 98 + (bx >> 3);    // 0..783, consecutive g share vb
  int b  = g & 7;
  int vb = g >> 3;                // 0..97
  int wv = threadIdx.x >> 6;
  int l  = threadIdx.x & 63;
  int col = l & 15, rowg = l >> 4;
  int vbase = vb * 8 + wv * 2;    // global v of this wave's v-local 0

  bf16x8 A[2][4];
#pragma unroll
  for (int v = 0; v < 2; ++v) {
    const unsigned short* ap = sk_f + (size_t)(vbase + v) * 2048 + rowg * 128 + col * 8;
#pragma unroll
    for (int s = 0; s < 4; ++s) A[v][s] = *(const bf16x8*)(ap + s * 512);
  }

  float wl[2][4];
#pragma unroll
  for (int v = 0; v < 2; ++v)
#pragma unroll
    for (int j = 0; j < 4; ++j) wl[v][j] = 0.f;

  const unsigned short* qb = q_f + (size_t)b * 100352 + rowg * 128 + col * 8;
  f32x4 zero = {0.f, 0.f, 0.f, 0.f};

  bf16x8 B0 = *(const bf16x8*)(qb);
  bf16x8 B1 = *(const bf16x8*)(qb + 512);
  bf16x8 B2 = *(const bf16x8*)(qb + 1024);
  bf16x8 B3 = *(const bf16x8*)(qb + 1536);

  for (int it = 0; it < 49; ++it) {
    int nit = (it + 1 < 49) ? it + 1 : it;
    const unsigned short* qp = qb + (size_t)nit * 2048;
    bf16x8 N0 = *(const bf16x8*)(qp);
    bf16x8 N1 = *(const bf16x8*)(qp + 512);
    bf16x8 N2 = *(const bf16x8*)(qp + 1024);
    bf16x8 N3 = *(const bf16x8*)(qp + 1536);

    f32x4 acc[2];
#pragma unroll
    for (int v = 0; v < 2; ++v)
      acc[v] = __builtin_amdgcn_mfma_f32_16x16x32_bf16(A[v][0], B0, zero, 0, 0, 0);
#pragma unroll
    for (int v = 0; v < 2; ++v)
      acc[v] = __builtin_amdgcn_mfma_f32_16x16x32_bf16(A[v][1], B1, acc[v], 0, 0, 0);
#pragma unroll
    for (int v = 0; v < 2; ++v)
      acc[v] = __builtin_amdgcn_mfma_f32_16x16x32_bf16(A[v][2], B2, acc[v], 0, 0, 0);
#pragma unroll
    for (int v = 0; v < 2; ++v)
      acc[v] = __builtin_amdgcn_mfma_f32_16x16x32_bf16(A[v][3], B3, acc[v], 0, 0, 0);

    float e[2][4], ps[2];
#pragma unroll
    for (int v = 0; v < 2; ++v) {
      e[v][0] = __builtin_amdgcn_exp2f(acc[v][0]);
      e[v][1] = __builtin_amdgcn_exp2f(acc[v][1]);
      e[v][2] = __builtin_amdgcn_exp2f(acc[v][2]);
      e[v][3] = __builtin_amdgcn_exp2f(acc[v][3]);
      ps[v] = (e[v][0] + e[v][1]) + (e[v][2] + e[v][3]);
    }
#pragma unroll
    for (int v = 0; v < 2; ++v) ps[v] = rowg_sum(ps[v]);
#pragma unroll
    for (int v = 0; v < 2; ++v) {
      float r = __builtin_amdgcn_rcpf(ps[v]);
      wl[v][0] += e[v][0] * r; wl[v][1] += e[v][1] * r;
      wl[v][2] += e[v][2] * r; wl[v][3] += e[v][3] * r;
    }
    B0 = N0; B1 = N1; B2 = N2; B3 = N3;
  }

  // u-sum across the 16 lane-columns
#pragma unroll
  for (int v = 0; v < 2; ++v)
#pragma unroll
    for (int j = 0; j < 4; ++j) {
      float x2 = wl[v][j];
      x2 += __shfl_xor(x2, 1, 64); x2 += __shfl_xor(x2, 2, 64);
      x2 += __shfl_xor(x2, 4, 64); x2 += __shfl_xor(x2, 8, 64);
      wl[v][j] = x2;
    }
  __shared__ float wst[4][2][16];   // [wave][v_local][class]
#pragma unroll
  for (int v = 0; v < 2; ++v)
    if (col == v) {
#pragma unroll
      for (int j = 0; j < 4; ++j) wst[wv][v][rowg * 4 + j] = wl[v][j];
    }
  __syncthreads();

  // ---- fused align: a[v][k] = sum_n w[v][n]*sv_t[n][v][k]; T1 += a^2;
  //      T2 partial = sum_v a. Lanes own 2 consecutive k (k0 = l*2).
  __shared__ float red[4][128];
  __shared__ float t1s[4];
  int k0 = l * 2;
  float a00 = 0.f, a01 = 0.f, a10 = 0.f, a11 = 0.f;   // [v][kk]
#pragma unroll
  for (int n = 0; n < NS; ++n) {
    float w0 = wst[wv][0][n], w1 = wst[wv][1][n];
    const float* p0 = sv_t + ((size_t)n * U_CNT + vbase) * DKH + k0;
    float2 s0 = *(const float2*)(p0);
    float2 s1 = *(const float2*)(p0 + DKH);
    a00 += w0 * s0.x; a01 += w0 * s0.y;
    a10 += w1 * s1.x; a11 += w1 * s1.y;
  }
  float t1 = a00 * a00 + a01 * a01 + a10 * a10 + a11 * a11;
  red[wv][k0] = a00 + a10;
  red[wv][k0 + 1] = a01 + a11;
#pragma unroll
  for (int o = 32; o >= 1; o >>= 1) t1 += __shfl_xor(t1, o, 64);
  if (l == 0) t1s[wv] = t1;
  __syncthreads();
  int t = threadIdx.x;
  if (t < 128)
    T2p[((size_t)vb * 8 + b) * DKH + t] = red[0][t] + red[1][t] + red[2][t] + red[3][t];
  if (t == 128)
    T1p[vb * 8 + b] = t1s[0] + t1s[1] + t1s[2] + t1s[3];
}

// ------------------------------- K5a: parallel partial reduction (40 blocks)
__global__ __launch_bounds__(256)
void reduce_partials(const float* __restrict__ S1p, const float* __restrict__ T1p,
                     const float* __restrict__ S2p, const float* __restrict__ T2p,
                     float* __restrict__ S2, float* __restrict__ T2,
                     float* __restrict__ ST1) {
  __shared__ float smem[264];
  int bx = blockIdx.x, t = threadIdx.x;
  if (bx < 32) {
    int b = bx >> 2, kq = bx & 3;
    int kl = t & 31, g = t >> 5;           // 8 groups x 32 k-lanes
    int k = kq * 32 + kl;
    float s = 0.f;
    for (int w = g; w < 98; w += 8)
      s += T2p[((size_t)w * 8 + b) * DKH + k];
    smem[g * 32 + kl] = s;
    __syncthreads();
    if (t < 32) {
      float v = 0.f;
#pragma unroll
      for (int g2 = 0; g2 < 8; ++g2) v += smem[g2 * 32 + t];
      T2[b * DKH + kq * 32 + t] = v;
    }
  } else {
    int b = bx - 32;
    int k = t & 127, h = t >> 7;
    float s = 0.f;
    for (int w = h; w < 49; w += 2)
      s += S2p[((size_t)w * 8 + b) * DKH + k];
    if (h == 1) smem[k] = s;
    __syncthreads();
    if (h == 0) S2[b * DKH + k] = s + smem[k];
    float c = 0.f;
    for (int i = t; i < 98; i += 256) c += S1p[i * 8 + b];
    for (int i = t; i < 98; i += 256) c += T1p[i * 8 + b];
#pragma unroll
    for (int o = 32; o >= 1; o >>= 1) c += __shfl_xor(c, o, 64);
    if ((t & 63) == 0) smem[256 + (t >> 6)] = c;
    __syncthreads();
    if (t == 0) ST1[b] = smem[256] + smem[257] + smem[258] + smem[259];
  }
}

// ----------------------------------------------------------------- K5b: final
__global__ void final_kernel(const float* __restrict__ S2, const float* __restrict__ T2,
                             const float* __restrict__ ST1, float* __restrict__ out) {
  int b = blockIdx.x, t = threadIdx.x;  // 128 threads
  float p = S2[b * DKH + t] * T2[b * DKH + t];
#pragma unroll
  for (int o = 32; o >= 1; o >>= 1) p += __shfl_xor(p, o, 64);
  __shared__ float s2[2];
  if ((t & 63) == 0) s2[t >> 6] = p;
  __syncthreads();
  if (t == 0)
    out[b] = (784.0f * ST1[b] - 2.0f * (s2[0] + s2[1])) * (1.0f / (784.0f * 784.0f));
}

// ----------------------------------------------------------------- launcher
extern "C" void kernel_launch(void* const* d_in, const int* in_sizes, int n_in,
                              void* d_out, int out_size, void* d_ws, size_t ws_size,
                              hipStream_t stream) {
  const float* query   = (const float*)d_in[0];
  const float* support = (const float*)d_in[1];
  const float* Wk      = (const float*)d_in[2];
  const float* Wv      = (const float*)d_in[3];
  float* out = (float*)d_out;
  char* ws = (char*)d_ws;

  // workspace layout (256B-aligned)
  unsigned short* Wkv  = (unsigned short*)(ws + 0);          //  256KB (fragment-major)
  unsigned short* q_f  = (unsigned short*)(ws + 262144);     //  bf16 [8][49][16][16][8] 1.53MB
  unsigned short* sk_f = (unsigned short*)(ws + 1867776);    //  bf16 [784][16][16][8]   3.06MB
  float*          sv_t = (float*)(ws + 5079040);             //  f32  [16][784][128]     6.13MB
  float*          T1p  = (float*)(ws + 11501568);            //  [98][8]
  float*          S1p  = (float*)(ws + 11504896);            //  [98][8]
  float*          S2p  = (float*)(ws + 11508224);            //  [49][8][128]
  float*          T2p  = (float*)(ws + 11708928);            //  [98][8][128]
  float*          S2   = (float*)(ws + 12110336);            //  [8][128]
  float*          T2   = (float*)(ws + 12114432);            //  [8][128]
  float*          ST1  = (float*)(ws + 12118528);            //  [8]
  if (ws_size < (size_t)12118784) return;

  cast_w<<<64, 256, 0, stream>>>(Wk, Wv, Wkv);
  proj_kernel<<<dim3(49, 24), 256, 0, stream>>>(query, support, Wkv, q_f, sk_f, sv_t, S1p, S2p);
  score_kernel<<<784, 256, 0, stream>>>(q_f, sk_f, sv_t, T1p, T2p);
  reduce_partials<<<40, 256, 0, stream>>>(S1p, T1p, S2p, T2p, S2, T2, ST1);
  final_kernel<<<8, 128, 0, stream>>>(S2, T2, ST1, out);
}